// Round 1
// baseline (132.905 us; speedup 1.0000x reference)
//
#include <hip/hip_runtime.h>
#include <hip/hip_bf16.h>

#define NN 4096
#define FF 128
#define NC 80     // 64 value cols + 8 expEr cols + 1 ones col + 7 pad
#define LSTR 84   // LDS partial-tile row stride in floats (84%32=20 -> 2-way max)

typedef __attribute__((ext_vector_type(4))) float float4v;
typedef __attribute__((ext_vector_type(4))) unsigned int uint4v;
typedef __attribute__((ext_vector_type(8))) short short8;

static __device__ inline unsigned short bfb(float x) {
    __hip_bfloat16 b = __float2bfloat16(x);
    return *(unsigned short*)&b;
}
static __device__ inline float bff(unsigned short u) {
    __hip_bfloat16 b = *(__hip_bfloat16*)&u;
    return __bfloat162float(b);
}
static __device__ inline uint4v ntload(const unsigned int* p) {
    return __builtin_nontemporal_load((const uint4v*)p);
}

// ---------------------------------------------------------------------------
// Kernel 0: one-shot W split. Computes the 80-column B-operand panel
// (64 value cols W[h,f,u], 8 contracted wr cols, 8 contracted wl cols) as
// hi/lo bf16 in MFMA B-fragment layout:
//   Wp[(g*NC + c)*8 + (f&7)],  g = (f>>5)*4 + ((f>>3)&3)
// Previously every prep block redid this (64 scalar loads + ~700 VALU/lane).
// ---------------------------------------------------------------------------
__global__ __launch_bounds__(640) void gat_wsplit(const float* __restrict__ W,
                                                  const float* __restrict__ al,
                                                  const float* __restrict__ ar,
                                                  __hip_bfloat16* __restrict__ Wphi,
                                                  __hip_bfloat16* __restrict__ Wplo)
{
    const int c  = threadIdx.x;        // 0..79 (column)
    const int f0 = threadIdx.y * 16;   // f-group
    float av[8];
    const int hc = (c - 64) & 7;
    if (c >= 64) {
        const float* ap = (c < 72) ? ar : al;
        #pragma unroll
        for (int u = 0; u < 8; ++u) av[u] = ap[hc * 8 + u];
    }
    #pragma unroll
    for (int i = 0; i < 16; ++i) {
        const int f = f0 + i;
        float val;
        if (c < 64) {
            val = W[(size_t)(c >> 3) * (FF * 8) + (size_t)f * 8 + (c & 7)];
        } else {
            const float* wp = W + (size_t)hc * (FF * 8) + (size_t)f * 8;
            float s = 0.f;
            #pragma unroll
            for (int u = 0; u < 8; ++u) s += wp[u] * av[u];
            val = s;
        }
        const unsigned short h = bfb(val);
        const unsigned short l = bfb(val - bff(h));
        const int g = (f >> 5) * 4 + ((f >> 3) & 3);
        const size_t idx = ((size_t)g * NC + c) * 8 + (f & 7);
        Wphi[idx] = *(const __hip_bfloat16*)&h;
        Wplo[idx] = *(const __hip_bfloat16*)&l;
    }
}

// ---------------------------------------------------------------------------
// Kernel 1 (MFMA prep): HW = H@W via split-bf16 (hi+lo residual, 3 cross-term
// MFMAs -> ~2^-17 rel err). 256 blocks x 1 wave x 16 rows. H fragments are
// loaded DIRECTLY from global (2 x float4 per lane per kt, each byte touched
// once) and split in registers -- no LDS, no staging barriers. W fragments
// come pre-split from gat_wsplit (L2-resident, lane-addressable).
// Writes Bp (bf16, B-fragment layout) and expEl[h*NN+j] (f32), as before.
// ---------------------------------------------------------------------------
__global__ __launch_bounds__(64) void gat_prep(const float* __restrict__ H,
                                               const __hip_bfloat16* __restrict__ Wphi,
                                               const __hip_bfloat16* __restrict__ Wplo,
                                               float* __restrict__ expEl,
                                               __hip_bfloat16* __restrict__ Bp)
{
    const int lane = threadIdx.x;
    const int j0 = blockIdx.x * 16;
    const int m16 = lane & 15, q = lane >> 4;
    const short* Whs = (const short*)Wphi;
    const short* Wls = (const short*)Wplo;

    float4v acc[5] = {};
    #pragma unroll
    for (int kt = 0; kt < 4; ++kt) {
        // A-fragment: lane (q,m16) holds H[j0+m16][kt*32 + q*8 .. +7]
        const float* hp = H + (size_t)(j0 + m16) * FF + kt * 32 + q * 8;
        float4v x0 = *(const float4v*)hp;
        float4v x1 = *(const float4v*)(hp + 4);
        short8 ahi, alo;
        #pragma unroll
        for (int i = 0; i < 4; ++i) {
            const unsigned short h0 = bfb(x0[i]);
            ahi[i] = (short)h0;
            alo[i] = (short)bfb(x0[i] - bff(h0));
            const unsigned short h1 = bfb(x1[i]);
            ahi[4 + i] = (short)h1;
            alo[4 + i] = (short)bfb(x1[i] - bff(h1));
        }
        const short8* bh = (const short8*)(Whs + (size_t)(kt * 4 + q) * NC * 8);
        const short8* bl = (const short8*)(Wls + (size_t)(kt * 4 + q) * NC * 8);
        #pragma unroll
        for (int nt = 0; nt < 5; ++nt) {
            short8 bhi = bh[nt * 16 + m16];
            short8 blo = bl[nt * 16 + m16];
            acc[nt] = __builtin_amdgcn_mfma_f32_16x16x32_bf16(ahi, bhi, acc[nt], 0, 0, 0);
            acc[nt] = __builtin_amdgcn_mfma_f32_16x16x32_bf16(alo, bhi, acc[nt], 0, 0, 0);
            acc[nt] = __builtin_amdgcn_mfma_f32_16x16x32_bf16(ahi, blo, acc[nt], 0, 0, 0);
        }
    }

    // acc[4] col 64+m16: m16<8 -> e_r[h=m16]; m16>=8 -> e_l[h=m16-8]
    const int jbase = j0 + q * 4;
    float ex[4];
    #pragma unroll
    for (int r = 0; r < 4; ++r) ex[r] = expf(acc[4][r]);
    if (m16 >= 8) {
        #pragma unroll
        for (int r = 0; r < 4; ++r)
            expEl[(m16 - 8) * NN + jbase + r] = ex[r];
    }
    #pragma unroll
    for (int r = 0; r < 4; ++r) {
        const int j = jbase + r;
        const size_t base = ((size_t)((j >> 5) * 4 + ((j >> 3) & 3)) * NC) * 8 + (j & 7);
        #pragma unroll
        for (int nt = 0; nt < 4; ++nt) {
            // col c = nt*16+m16 -> h = 2nt + (m16>>3); expEr[h] lives on lane (q, m16'=h)
            const int srcl = (lane & 48) | (nt * 2 + (m16 >> 3));
            const float er = __shfl(ex[r], srcl);
            Bp[base + (size_t)(nt * 16 + m16) * 8] = __float2bfloat16(er * acc[nt][r]);
        }
        const float v = (m16 < 8) ? ex[r] : (m16 == 8 ? 1.0f : 0.0f);
        Bp[base + (size_t)(64 + m16) * 8] = __float2bfloat16(v);
    }
}

// ---------------------------------------------------------------------------
// Kernel 2 (fused, block-local split-K): block = 1024 thr (16 waves), 16 rows.
// Wave w computes the 16x80 tile over K-chunk [w*256, (w+1)*256); partials
// reduced through LDS, then denom + elu + store. Changes vs previous version:
//   - 16 waves/block (4/SIMD) + depth-2 A prefetch: ~64 KB HBM reads in
//     flight per CU (Little's law needs ~12 KB at 6.3 TB/s x ~1.2k cyc).
//   - A loads are NON-TEMPORAL: the one-shot 64 MB A stream no longer evicts
//     the 640 KB Bp panel from each XCD's L2, keeping B-fragment loads L2-hit.
// A f32 0/1 truncated to bf16 in-register (exact).
// ---------------------------------------------------------------------------
__global__ __launch_bounds__(1024) void gat_gemm(const float* __restrict__ A,
                                                 const __hip_bfloat16* __restrict__ Bp,
                                                 const float* __restrict__ expEl,
                                                 float* __restrict__ out)
{
    __shared__ float Ls[16 * 16 * LSTR];  // 86 KB (gfx950: 160 KB/WG ok)
    const int rb   = blockIdx.x;          // 0..255, 16 rows each
    const int wave = threadIdx.x >> 6;    // 0..15 = K-chunk
    const int lane = threadIdx.x & 63;
    const int m16  = lane & 15;
    const int q    = lane >> 4;
    const int row0 = rb * 16;

    float4v acc[5] = {};

    const int k0 = wave * 256;
    const unsigned int* Au = (const unsigned int*)A;
    const short* Bs = (const short*)Bp;
    const unsigned int* arow = Au + (size_t)(row0 + m16) * NN + q * 8 + k0;

    uint4v a0[2], a1[2];
    a0[0] = ntload(arow);      a1[0] = ntload(arow + 4);
    a0[1] = ntload(arow + 32); a1[1] = ntload(arow + 36);

    #pragma unroll
    for (int kt = 0; kt < 8; ++kt) {
        const int cur = kt & 1;           // compile-time after full unroll
        short8 afrag;
        afrag[0] = (short)(a0[cur][0] >> 16); afrag[1] = (short)(a0[cur][1] >> 16);
        afrag[2] = (short)(a0[cur][2] >> 16); afrag[3] = (short)(a0[cur][3] >> 16);
        afrag[4] = (short)(a1[cur][0] >> 16); afrag[5] = (short)(a1[cur][1] >> 16);
        afrag[6] = (short)(a1[cur][2] >> 16); afrag[7] = (short)(a1[cur][3] >> 16);

        if (kt + 2 < 8) {                 // depth-2 rolling prefetch
            a0[cur] = ntload(arow + (kt + 2) * 32);
            a1[cur] = ntload(arow + (kt + 2) * 32 + 4);
        }

        const int ktg = wave * 8 + kt;    // global 32-wide k-tile index
        const short8* bbase = (const short8*)(Bs + ((size_t)(ktg * 4 + q) * NC) * 8);
        #pragma unroll
        for (int nt = 0; nt < 5; ++nt) {
            short8 bfrag = bbase[nt * 16 + m16];
            acc[nt] = __builtin_amdgcn_mfma_f32_16x16x32_bf16(afrag, bfrag, acc[nt], 0, 0, 0);
        }
    }

    // ---- partials -> LDS (stride LSTR=84: q-groups land 16 banks apart) ----
    float* Lw = Ls + wave * (16 * LSTR);
    #pragma unroll
    for (int nt = 0; nt < 5; ++nt) {
        #pragma unroll
        for (int r = 0; r < 4; ++r)       // C/D: col=lane&15, row=(lane>>4)*4+reg
            Lw[(q * 4 + r) * LSTR + nt * 16 + m16] = acc[nt][r];
    }
    __syncthreads();

    // ---- reduce 16 wave-partials + denom + elu + store (1024 outputs) ----
    {
        const int p  = threadIdx.x;
        const int il = p >> 6;            // local row (one row per wave)
        const int c  = p & 63;            // h*8+u, contiguous per wave
        const int h  = c >> 3;
        float T = 0.f, S = 0.f, dg = 0.f;
        #pragma unroll
        for (int w = 0; w < 16; ++w) {
            const float* rowp = Ls + w * (16 * LSTR) + il * LSTR;
            T  += rowp[c];
            S  += rowp[64 + h];
            dg += rowp[72];
        }
        const float el = expEl[h * NN + row0 + il];
        const float denom = ((float)NN - dg) + el * S;
        const float x = el * T / denom;
        out[(size_t)(row0 + il) * 64 + c] = x > 0.f ? x : expf(x) - 1.f;
    }
}

extern "C" void kernel_launch(void* const* d_in, const int* in_sizes, int n_in,
                              void* d_out, int out_size, void* d_ws, size_t ws_size,
                              hipStream_t stream) {
    const float* A  = (const float*)d_in[0];
    const float* H  = (const float*)d_in[1];
    const float* W  = (const float*)d_in[2];
    const float* al = (const float*)d_in[3];
    const float* ar = (const float*)d_in[4];
    float* out = (float*)d_out;

    // workspace layout
    float* expEl = (float*)d_ws;                                    // 8*4096 f32 = 128 KB
    __hip_bfloat16* Bp   = (__hip_bfloat16*)((char*)d_ws + 131072); // 512*80*8 bf16 = 640 KB
    __hip_bfloat16* Wphi = (__hip_bfloat16*)((char*)d_ws + 131072 + 655360);          // 20 KB
    __hip_bfloat16* Wplo = (__hip_bfloat16*)((char*)d_ws + 131072 + 655360 + 20480);  // 20 KB

    gat_wsplit<<<1, dim3(80, 8), 0, stream>>>(W, al, ar, Wphi, Wplo);
    gat_prep<<<NN / 16, 64, 0, stream>>>(H, Wphi, Wplo, expEl, Bp);
    gat_gemm<<<NN / 16, 1024, 0, stream>>>(A, Bp, expEl, out);
}

// Round 2
// 119.753 us; speedup vs baseline: 1.1098x; 1.1098x over previous
//
#include <hip/hip_runtime.h>
#include <hip/hip_bf16.h>

#define NN 4096
#define FF 128
#define NC 80     // 64 value cols + 8 expEr cols + 1 ones col + 7 pad
#define LSTR 84   // LDS partial-tile row stride in floats (84%32=20 -> 2-way max)

typedef __attribute__((ext_vector_type(4))) float float4v;
typedef __attribute__((ext_vector_type(4))) unsigned int uint4v;
typedef __attribute__((ext_vector_type(8))) short short8;

static __device__ inline unsigned short bfb(float x) {
    __hip_bfloat16 b = __float2bfloat16(x);
    return *(unsigned short*)&b;
}
static __device__ inline float bff(unsigned short u) {
    __hip_bfloat16 b = *(__hip_bfloat16*)&u;
    return __bfloat162float(b);
}

// ---------------------------------------------------------------------------
// Kernel 0: one-shot W split, PARALLEL (40 blocks x 256 thr, one element per
// thread; round-1's single-block version serialized ~6 us on one CU).
// Computes the 80-column B-operand panel (64 value cols W[h,f,u], 8
// contracted wr cols, 8 contracted wl cols) as hi/lo bf16 in MFMA B-fragment
// layout:  Wp[(g*NC + c)*8 + (f&7)],  g = (f>>5)*4 + ((f>>3)&3)
// ---------------------------------------------------------------------------
__global__ __launch_bounds__(256) void gat_wsplit(const float* __restrict__ W,
                                                  const float* __restrict__ al,
                                                  const float* __restrict__ ar,
                                                  __hip_bfloat16* __restrict__ Wphi,
                                                  __hip_bfloat16* __restrict__ Wplo)
{
    const int tid = blockIdx.x * 256 + threadIdx.x;   // 0..10239
    if (tid >= 80 * FF) return;
    const int c = tid % 80;
    const int f = tid / 80;                           // 0..127
    float val;
    if (c < 64) {
        val = W[(size_t)(c >> 3) * (FF * 8) + (size_t)f * 8 + (c & 7)];
    } else {
        const int hc = (c - 64) & 7;
        const float* ap = (c < 72) ? ar : al;
        const float* wp = W + (size_t)hc * (FF * 8) + (size_t)f * 8;
        float s = 0.f;
        #pragma unroll
        for (int u = 0; u < 8; ++u) s += wp[u] * ap[hc * 8 + u];
        val = s;
    }
    const unsigned short h = bfb(val);
    const unsigned short l = bfb(val - bff(h));
    const int g = (f >> 5) * 4 + ((f >> 3) & 3);
    const size_t idx = ((size_t)g * NC + c) * 8 + (f & 7);
    Wphi[idx] = *(const __hip_bfloat16*)&h;
    Wplo[idx] = *(const __hip_bfloat16*)&l;
}

// ---------------------------------------------------------------------------
// Kernel 1 (MFMA prep): HW = H@W via split-bf16 (hi+lo residual, 3 cross-term
// MFMAs -> ~2^-17 rel err). 256 blocks x 1 wave x 16 rows. H fragments loaded
// DIRECTLY from global (2 x float4 per lane per kt) and split in registers --
// no LDS, no barriers. W fragments come pre-split from gat_wsplit (L2).
// __launch_bounds__(64,1): 1 wave/EU floor -> allocator free to hoist all
// independent loads (latency-bound kernel, ILP is the only hiding available).
// Writes Bp (bf16, B-fragment layout) and expEl[h*NN+j] (f32).
// ---------------------------------------------------------------------------
__global__ __launch_bounds__(64, 1) void gat_prep(const float* __restrict__ H,
                                                  const __hip_bfloat16* __restrict__ Wphi,
                                                  const __hip_bfloat16* __restrict__ Wplo,
                                                  float* __restrict__ expEl,
                                                  __hip_bfloat16* __restrict__ Bp)
{
    const int lane = threadIdx.x;
    const int j0 = blockIdx.x * 16;
    const int m16 = lane & 15, q = lane >> 4;
    const short* Whs = (const short*)Wphi;
    const short* Wls = (const short*)Wplo;

    float4v acc[5] = {};
    #pragma unroll
    for (int kt = 0; kt < 4; ++kt) {
        // A-fragment: lane (q,m16) holds H[j0+m16][kt*32 + q*8 .. +7]
        const float* hp = H + (size_t)(j0 + m16) * FF + kt * 32 + q * 8;
        float4v x0 = *(const float4v*)hp;
        float4v x1 = *(const float4v*)(hp + 4);
        short8 ahi, alo;
        #pragma unroll
        for (int i = 0; i < 4; ++i) {
            const unsigned short h0 = bfb(x0[i]);
            ahi[i] = (short)h0;
            alo[i] = (short)bfb(x0[i] - bff(h0));
            const unsigned short h1 = bfb(x1[i]);
            ahi[4 + i] = (short)h1;
            alo[4 + i] = (short)bfb(x1[i] - bff(h1));
        }
        const short8* bh = (const short8*)(Whs + (size_t)(kt * 4 + q) * NC * 8);
        const short8* bl = (const short8*)(Wls + (size_t)(kt * 4 + q) * NC * 8);
        #pragma unroll
        for (int nt = 0; nt < 5; ++nt) {
            short8 bhi = bh[nt * 16 + m16];
            short8 blo = bl[nt * 16 + m16];
            acc[nt] = __builtin_amdgcn_mfma_f32_16x16x32_bf16(ahi, bhi, acc[nt], 0, 0, 0);
            acc[nt] = __builtin_amdgcn_mfma_f32_16x16x32_bf16(alo, bhi, acc[nt], 0, 0, 0);
            acc[nt] = __builtin_amdgcn_mfma_f32_16x16x32_bf16(ahi, blo, acc[nt], 0, 0, 0);
        }
    }

    // acc[4] col 64+m16: m16<8 -> e_r[h=m16]; m16>=8 -> e_l[h=m16-8]
    const int jbase = j0 + q * 4;
    float ex[4];
    #pragma unroll
    for (int r = 0; r < 4; ++r) ex[r] = expf(acc[4][r]);
    if (m16 >= 8) {
        #pragma unroll
        for (int r = 0; r < 4; ++r)
            expEl[(m16 - 8) * NN + jbase + r] = ex[r];
    }
    #pragma unroll
    for (int r = 0; r < 4; ++r) {
        const int j = jbase + r;
        const size_t base = ((size_t)((j >> 5) * 4 + ((j >> 3) & 3)) * NC) * 8 + (j & 7);
        #pragma unroll
        for (int nt = 0; nt < 4; ++nt) {
            // col c = nt*16+m16 -> h = 2nt + (m16>>3); expEr[h] lives on lane (q, m16'=h)
            const int srcl = (lane & 48) | (nt * 2 + (m16 >> 3));
            const float er = __shfl(ex[r], srcl);
            Bp[base + (size_t)(nt * 16 + m16) * 8] = __float2bfloat16(er * acc[nt][r]);
        }
        const float v = (m16 < 8) ? ex[r] : (m16 == 8 ? 1.0f : 0.0f);
        Bp[base + (size_t)(64 + m16) * 8] = __float2bfloat16(v);
    }
}

// ---------------------------------------------------------------------------
// Kernel 2 (fused, block-local split-K): EXACT round-0 version (proven
// 116 us config). block = 512 thr (8 waves), 16 rows; wave w covers K-chunk
// [w*512,(w+1)*512). 43 KB LDS -> 2 blocks/CU: 4 waves/SIMD AND one block's
// GEMM overlaps the other block's barrier+reduction drain (lost in round-1's
// 1024-thr variant). Plain loads, depth-1 in-loop prefetch.
// ---------------------------------------------------------------------------
__global__ __launch_bounds__(512) void gat_gemm(const float* __restrict__ A,
                                                const __hip_bfloat16* __restrict__ Bp,
                                                const float* __restrict__ expEl,
                                                float* __restrict__ out)
{
    __shared__ float Ls[8 * 16 * LSTR];   // 43 KB
    const int rb   = blockIdx.x;          // 0..255, 16 rows each
    const int wave = threadIdx.x >> 6;    // 0..7 = K-chunk
    const int lane = threadIdx.x & 63;
    const int m16  = lane & 15;
    const int q    = lane >> 4;
    const int row0 = rb * 16;

    float4v acc[5] = {};

    const int k0 = wave * 512;
    const unsigned int* Au = (const unsigned int*)A;
    const short* Bs = (const short*)Bp;
    const unsigned int* arow = Au + (size_t)(row0 + m16) * NN + q * 8;

    uint4v a0 = *(const uint4v*)(arow + k0);
    uint4v a1 = *(const uint4v*)(arow + k0 + 4);

    #pragma unroll 4
    for (int kt = 0; kt < 16; ++kt) {
        const int kk = k0 + kt * 32;
        short8 afrag;
        afrag[0] = (short)(a0[0] >> 16); afrag[1] = (short)(a0[1] >> 16);
        afrag[2] = (short)(a0[2] >> 16); afrag[3] = (short)(a0[3] >> 16);
        afrag[4] = (short)(a1[0] >> 16); afrag[5] = (short)(a1[1] >> 16);
        afrag[6] = (short)(a1[2] >> 16); afrag[7] = (short)(a1[3] >> 16);

        if (kt + 1 < 16) {                // prefetch next A tile
            a0 = *(const uint4v*)(arow + kk + 32);
            a1 = *(const uint4v*)(arow + kk + 36);
        }

        const int ktg = kk >> 5;
        const short8* bbase = (const short8*)(Bs + ((size_t)(ktg * 4 + q) * NC) * 8);
        #pragma unroll
        for (int nt = 0; nt < 5; ++nt) {
            short8 bfrag = bbase[nt * 16 + m16];
            acc[nt] = __builtin_amdgcn_mfma_f32_16x16x32_bf16(afrag, bfrag, acc[nt], 0, 0, 0);
        }
    }

    // ---- partials -> LDS (stride LSTR=84: q-groups land 16 banks apart) ----
    float* Lw = Ls + wave * (16 * LSTR);
    #pragma unroll
    for (int nt = 0; nt < 5; ++nt) {
        #pragma unroll
        for (int r = 0; r < 4; ++r)       // C/D: col=lane&15, row=(lane>>4)*4+reg
            Lw[(q * 4 + r) * LSTR + nt * 16 + m16] = acc[nt][r];
    }
    __syncthreads();

    // ---- reduce 8 wave-partials + denom + elu + store (1024 outputs) ----
    #pragma unroll
    for (int p = threadIdx.x; p < 1024; p += 512) {
        const int il = p >> 6;            // local row
        const int c  = p & 63;            // h*8+u
        const int h  = c >> 3;
        float T = 0.f, S = 0.f, dg = 0.f;
        #pragma unroll
        for (int w = 0; w < 8; ++w) {
            const float* rowp = Ls + w * (16 * LSTR) + il * LSTR;
            T  += rowp[c];
            S  += rowp[64 + h];
            dg += rowp[72];
        }
        const float el = expEl[h * NN + row0 + il];
        const float denom = ((float)NN - dg) + el * S;
        const float x = el * T / denom;
        out[(size_t)(row0 + il) * 64 + c] = x > 0.f ? x : expf(x) - 1.f;
    }
}

extern "C" void kernel_launch(void* const* d_in, const int* in_sizes, int n_in,
                              void* d_out, int out_size, void* d_ws, size_t ws_size,
                              hipStream_t stream) {
    const float* A  = (const float*)d_in[0];
    const float* H  = (const float*)d_in[1];
    const float* W  = (const float*)d_in[2];
    const float* al = (const float*)d_in[3];
    const float* ar = (const float*)d_in[4];
    float* out = (float*)d_out;

    // workspace layout
    float* expEl = (float*)d_ws;                                    // 8*4096 f32 = 128 KB
    __hip_bfloat16* Bp   = (__hip_bfloat16*)((char*)d_ws + 131072); // 512*80*8 bf16 = 640 KB
    __hip_bfloat16* Wphi = (__hip_bfloat16*)((char*)d_ws + 131072 + 655360);          // 20 KB
    __hip_bfloat16* Wplo = (__hip_bfloat16*)((char*)d_ws + 131072 + 655360 + 20480);  // 20 KB

    gat_wsplit<<<40, 256, 0, stream>>>(W, al, ar, Wphi, Wplo);
    gat_prep<<<NN / 16, 64, 0, stream>>>(H, Wphi, Wplo, expEl, Bp);
    gat_gemm<<<NN / 16, 512, 0, stream>>>(A, Bp, expEl, out);
}

// Round 3
// 118.385 us; speedup vs baseline: 1.1226x; 1.0116x over previous
//
#include <hip/hip_runtime.h>
#include <hip/hip_bf16.h>

#define NN 4096
#define FF 128
#define NC 80     // 64 value cols + 8 expEr cols + 1 ones col + 7 pad
#define LSTR 84   // LDS partial-tile row stride in floats (84%32=20 -> 2-way max)

typedef __attribute__((ext_vector_type(4))) float float4v;
typedef __attribute__((ext_vector_type(4))) unsigned int uint4v;
typedef __attribute__((ext_vector_type(8))) short short8;

static __device__ inline unsigned short bfb(float x) {
    __hip_bfloat16 b = __float2bfloat16(x);
    return *(unsigned short*)&b;
}
static __device__ inline float bff(unsigned short u) {
    __hip_bfloat16 b = *(__hip_bfloat16*)&u;
    return __bfloat162float(b);
}

// ---------------------------------------------------------------------------
// Kernel 0: one-shot W split, parallel (40 blocks x 256 thr, one element per
// thread). Computes the 80-column B-operand panel (64 value cols W[h,f,u],
// 8 contracted wr cols, 8 contracted wl cols) as hi/lo bf16 in MFMA
// B-fragment layout:  Wp[(g*NC + c)*8 + (f&7)],  g = (f>>5)*4 + ((f>>3)&3)
// ---------------------------------------------------------------------------
__global__ __launch_bounds__(256) void gat_wsplit(const float* __restrict__ W,
                                                  const float* __restrict__ al,
                                                  const float* __restrict__ ar,
                                                  __hip_bfloat16* __restrict__ Wphi,
                                                  __hip_bfloat16* __restrict__ Wplo)
{
    const int tid = blockIdx.x * 256 + threadIdx.x;   // 0..10239
    if (tid >= 80 * FF) return;
    const int c = tid % 80;
    const int f = tid / 80;                           // 0..127
    float val;
    if (c < 64) {
        val = W[(size_t)(c >> 3) * (FF * 8) + (size_t)f * 8 + (c & 7)];
    } else {
        const int hc = (c - 64) & 7;
        const float* ap = (c < 72) ? ar : al;
        const float* wp = W + (size_t)hc * (FF * 8) + (size_t)f * 8;
        float s = 0.f;
        #pragma unroll
        for (int u = 0; u < 8; ++u) s += wp[u] * ap[hc * 8 + u];
        val = s;
    }
    const unsigned short h = bfb(val);
    const unsigned short l = bfb(val - bff(h));
    const int g = (f >> 5) * 4 + ((f >> 3) & 3);
    const size_t idx = ((size_t)g * NC + c) * 8 + (f & 7);
    Wphi[idx] = *(const __hip_bfloat16*)&h;
    Wplo[idx] = *(const __hip_bfloat16*)&l;
}

// ---------------------------------------------------------------------------
// Kernel 1 (MFMA prep): HW = H@W, split-bf16 (hi+lo, 3 cross-term MFMAs).
// NEW: 256 blocks x 256 thr (4 waves). Round-2 ran 1 wave/CU with a ~48-load
// + 45-MFMA serial chain and 3/4 SIMDs idle. Now wave w owns K-slice kt=w
// (2 H loads + 10 B loads + 15 MFMAs each -> chain cut ~4x), partials are
// combined through LDS, and the epilogue reads the combined tile from LDS
// directly (h = c>>3 indexing) -- no cross-lane shuffles needed.
// Writes Bp (bf16, B-fragment layout) and expEl[h*NN+j] (f32).
// ---------------------------------------------------------------------------
__global__ __launch_bounds__(256) void gat_prep(const float* __restrict__ H,
                                                const __hip_bfloat16* __restrict__ Wphi,
                                                const __hip_bfloat16* __restrict__ Wplo,
                                                float* __restrict__ expEl,
                                                __hip_bfloat16* __restrict__ Bp)
{
    __shared__ float Lp[4 * 16 * LSTR];   // 21.5 KB
    const int t    = threadIdx.x;
    const int wave = t >> 6;              // 0..3 = kt (K-slice of 32)
    const int lane = t & 63;
    const int j0   = blockIdx.x * 16;
    const int m16  = lane & 15, q = lane >> 4;
    const short* Whs = (const short*)Wphi;
    const short* Wls = (const short*)Wplo;
    const int kt = wave;

    // A-fragment: lane (q,m16) holds H[j0+m16][kt*32 + q*8 .. +7]
    const float* hp = H + (size_t)(j0 + m16) * FF + kt * 32 + q * 8;
    float4v x0 = *(const float4v*)hp;
    float4v x1 = *(const float4v*)(hp + 4);
    short8 ahi, alo;
    #pragma unroll
    for (int i = 0; i < 4; ++i) {
        const unsigned short h0 = bfb(x0[i]);
        ahi[i] = (short)h0;
        alo[i] = (short)bfb(x0[i] - bff(h0));
        const unsigned short h1 = bfb(x1[i]);
        ahi[4 + i] = (short)h1;
        alo[4 + i] = (short)bfb(x1[i] - bff(h1));
    }

    const short8* bh = (const short8*)(Whs + (size_t)(kt * 4 + q) * NC * 8);
    const short8* bl = (const short8*)(Wls + (size_t)(kt * 4 + q) * NC * 8);
    float4v acc[5] = {};
    #pragma unroll
    for (int nt = 0; nt < 5; ++nt) {
        short8 bhi = bh[nt * 16 + m16];
        short8 blo = bl[nt * 16 + m16];
        acc[nt] = __builtin_amdgcn_mfma_f32_16x16x32_bf16(ahi, bhi, acc[nt], 0, 0, 0);
        acc[nt] = __builtin_amdgcn_mfma_f32_16x16x32_bf16(alo, bhi, acc[nt], 0, 0, 0);
        acc[nt] = __builtin_amdgcn_mfma_f32_16x16x32_bf16(ahi, blo, acc[nt], 0, 0, 0);
    }

    // partial -> LDS (C/D layout: col=lane&15, row=(lane>>4)*4+reg)
    float* Lw = Lp + wave * (16 * LSTR);
    #pragma unroll
    for (int nt = 0; nt < 5; ++nt) {
        #pragma unroll
        for (int r = 0; r < 4; ++r)
            Lw[(q * 4 + r) * LSTR + nt * 16 + m16] = acc[nt][r];
    }
    __syncthreads();

    // ---- epilogue: 256 thr, thread (jl = t>>4, g = t&15) ----
    const int jl = t >> 4, g = t & 15;
    const float* Lr = Lp + jl * LSTR;
    const int jg = j0 + jl;
    const size_t base = ((size_t)((jg >> 5) * 4 + ((jg >> 3) & 3)) * NC) * 8 + (jg & 7);

    #pragma unroll
    for (int i = 0; i < 4; ++i) {
        const int c = g + 16 * i;                 // value col, h = c>>3
        const int h = (g >> 3) + 2 * i;
        const float er = expf(Lr[64 + h] + Lr[16 * LSTR + 64 + h] +
                              Lr[32 * LSTR + 64 + h] + Lr[48 * LSTR + 64 + h]);
        const float v = Lr[c] + Lr[16 * LSTR + c] +
                        Lr[32 * LSTR + c] + Lr[48 * LSTR + c];
        Bp[base + (size_t)c * 8] = __float2bfloat16(er * v);
    }
    float v64;
    if (g < 8) {
        v64 = expf(Lr[64 + g] + Lr[16 * LSTR + 64 + g] +
                   Lr[32 * LSTR + 64 + g] + Lr[48 * LSTR + 64 + g]);
    } else {
        v64 = (g == 8) ? 1.0f : 0.0f;
    }
    Bp[base + (size_t)(64 + g) * 8] = __float2bfloat16(v64);
    if (g >= 8) {
        const int h = g - 8;
        expEl[h * NN + jg] = expf(Lr[72 + h] + Lr[16 * LSTR + 72 + h] +
                                  Lr[32 * LSTR + 72 + h] + Lr[48 * LSTR + 72 + h]);
    }
}

// ---------------------------------------------------------------------------
// Kernel 2 (fused, block-local split-K): proven 512-thr structure, 8 waves,
// 16 rows, wave w covers K-chunk [w*512,(w+1)*512). ONLY change vs round-2:
// depth-2 A prefetch. Depth-1 held 2 KB/wave x 8 waves = 16 KB/CU in flight
// vs ~12-15 KB needed at loaded HBM latency (10.25 B/cyc x ~1.2-1.5k cyc) --
// marginal, so waves hit vmcnt stalls. Depth-2 -> 32 KB/CU, robust coverage.
// A f32 0/1 truncated to bf16 in-register (exact).
// ---------------------------------------------------------------------------
__global__ __launch_bounds__(512) void gat_gemm(const float* __restrict__ A,
                                                const __hip_bfloat16* __restrict__ Bp,
                                                const float* __restrict__ expEl,
                                                float* __restrict__ out)
{
    __shared__ float Ls[8 * 16 * LSTR];   // 43 KB
    const int rb   = blockIdx.x;          // 0..255, 16 rows each
    const int wave = threadIdx.x >> 6;    // 0..7 = K-chunk
    const int lane = threadIdx.x & 63;
    const int m16  = lane & 15;
    const int q    = lane >> 4;
    const int row0 = rb * 16;

    float4v acc[5] = {};

    const int k0 = wave * 512;
    const unsigned int* Au = (const unsigned int*)A;
    const short* Bs = (const short*)Bp;
    const unsigned int* arow = Au + (size_t)(row0 + m16) * NN + q * 8 + k0;

    uint4v a0[2], a1[2];
    a0[0] = *(const uint4v*)(arow);      a1[0] = *(const uint4v*)(arow + 4);
    a0[1] = *(const uint4v*)(arow + 32); a1[1] = *(const uint4v*)(arow + 36);

    #pragma unroll
    for (int kt = 0; kt < 16; ++kt) {
        const int cur = kt & 1;           // static after full unroll
        short8 afrag;
        afrag[0] = (short)(a0[cur][0] >> 16); afrag[1] = (short)(a0[cur][1] >> 16);
        afrag[2] = (short)(a0[cur][2] >> 16); afrag[3] = (short)(a0[cur][3] >> 16);
        afrag[4] = (short)(a1[cur][0] >> 16); afrag[5] = (short)(a1[cur][1] >> 16);
        afrag[6] = (short)(a1[cur][2] >> 16); afrag[7] = (short)(a1[cur][3] >> 16);

        if (kt + 2 < 16) {                // depth-2 rolling prefetch
            a0[cur] = *(const uint4v*)(arow + (kt + 2) * 32);
            a1[cur] = *(const uint4v*)(arow + (kt + 2) * 32 + 4);
        }

        const int ktg = (k0 >> 5) + kt;   // global 32-wide k-tile index
        const short8* bbase = (const short8*)(Bs + ((size_t)(ktg * 4 + q) * NC) * 8);
        #pragma unroll
        for (int nt = 0; nt < 5; ++nt) {
            short8 bfrag = bbase[nt * 16 + m16];
            acc[nt] = __builtin_amdgcn_mfma_f32_16x16x32_bf16(afrag, bfrag, acc[nt], 0, 0, 0);
        }
    }

    // ---- partials -> LDS (stride LSTR=84: q-groups land 16 banks apart) ----
    float* Lw = Ls + wave * (16 * LSTR);
    #pragma unroll
    for (int nt = 0; nt < 5; ++nt) {
        #pragma unroll
        for (int r = 0; r < 4; ++r)       // C/D: col=lane&15, row=(lane>>4)*4+reg
            Lw[(q * 4 + r) * LSTR + nt * 16 + m16] = acc[nt][r];
    }
    __syncthreads();

    // ---- reduce 8 wave-partials + denom + elu + store (1024 outputs) ----
    #pragma unroll
    for (int p = threadIdx.x; p < 1024; p += 512) {
        const int il = p >> 6;            // local row
        const int c  = p & 63;            // h*8+u
        const int h  = c >> 3;
        float T = 0.f, S = 0.f, dg = 0.f;
        #pragma unroll
        for (int w = 0; w < 8; ++w) {
            const float* rowp = Ls + w * (16 * LSTR) + il * LSTR;
            T  += rowp[c];
            S  += rowp[64 + h];
            dg += rowp[72];
        }
        const float el = expEl[h * NN + row0 + il];
        const float denom = ((float)NN - dg) + el * S;
        const float x = el * T / denom;
        out[(size_t)(row0 + il) * 64 + c] = x > 0.f ? x : expf(x) - 1.f;
    }
}

extern "C" void kernel_launch(void* const* d_in, const int* in_sizes, int n_in,
                              void* d_out, int out_size, void* d_ws, size_t ws_size,
                              hipStream_t stream) {
    const float* A  = (const float*)d_in[0];
    const float* H  = (const float*)d_in[1];
    const float* W  = (const float*)d_in[2];
    const float* al = (const float*)d_in[3];
    const float* ar = (const float*)d_in[4];
    float* out = (float*)d_out;

    // workspace layout
    float* expEl = (float*)d_ws;                                    // 8*4096 f32 = 128 KB
    __hip_bfloat16* Bp   = (__hip_bfloat16*)((char*)d_ws + 131072); // 512*80*8 bf16 = 640 KB
    __hip_bfloat16* Wphi = (__hip_bfloat16*)((char*)d_ws + 131072 + 655360);          // 20 KB
    __hip_bfloat16* Wplo = (__hip_bfloat16*)((char*)d_ws + 131072 + 655360 + 20480);  // 20 KB

    gat_wsplit<<<40, 256, 0, stream>>>(W, al, ar, Wphi, Wplo);
    gat_prep<<<NN / 16, 256, 0, stream>>>(H, Wphi, Wplo, expEl, Bp);
    gat_gemm<<<NN / 16, 512, 0, stream>>>(A, Bp, expEl, out);
}

// Round 4
// 118.210 us; speedup vs baseline: 1.1243x; 1.0015x over previous
//
#include <hip/hip_runtime.h>
#include <hip/hip_bf16.h>

#define NN 4096
#define FF 128
#define NC 80     // 64 value cols + 8 expEr cols + 1 ones col + 7 pad
#define LSTR 84   // LDS partial-tile row stride in floats (84%32=20 -> 2-way max)

typedef __attribute__((ext_vector_type(4))) float float4v;
typedef __attribute__((ext_vector_type(4))) unsigned int uint4v;
typedef __attribute__((ext_vector_type(8))) short short8;

static __device__ inline unsigned short bfb(float x) {
    __hip_bfloat16 b = __float2bfloat16(x);
    return *(unsigned short*)&b;
}
static __device__ inline float bff(unsigned short u) {
    __hip_bfloat16 b = *(__hip_bfloat16*)&u;
    return __bfloat162float(b);
}

// ---------------------------------------------------------------------------
// Kernel 0: one-shot W split, parallel (40 blocks x 256 thr, one element per
// thread). Computes the 80-column B-operand panel (64 value cols W[h,f,u],
// 8 contracted wr cols, 8 contracted wl cols) as hi/lo bf16 in MFMA
// B-fragment layout:  Wp[(g*NC + c)*8 + (f&7)],  g = (f>>5)*4 + ((f>>3)&3)
// UNCHANGED from round 3.
// ---------------------------------------------------------------------------
__global__ __launch_bounds__(256) void gat_wsplit(const float* __restrict__ W,
                                                  const float* __restrict__ al,
                                                  const float* __restrict__ ar,
                                                  __hip_bfloat16* __restrict__ Wphi,
                                                  __hip_bfloat16* __restrict__ Wplo)
{
    const int tid = blockIdx.x * 256 + threadIdx.x;   // 0..10239
    if (tid >= 80 * FF) return;
    const int c = tid % 80;
    const int f = tid / 80;                           // 0..127
    float val;
    if (c < 64) {
        val = W[(size_t)(c >> 3) * (FF * 8) + (size_t)f * 8 + (c & 7)];
    } else {
        const int hc = (c - 64) & 7;
        const float* ap = (c < 72) ? ar : al;
        const float* wp = W + (size_t)hc * (FF * 8) + (size_t)f * 8;
        float s = 0.f;
        #pragma unroll
        for (int u = 0; u < 8; ++u) s += wp[u] * ap[hc * 8 + u];
        val = s;
    }
    const unsigned short h = bfb(val);
    const unsigned short l = bfb(val - bff(h));
    const int g = (f >> 5) * 4 + ((f >> 3) & 3);
    const size_t idx = ((size_t)g * NC + c) * 8 + (f & 7);
    Wphi[idx] = *(const __hip_bfloat16*)&h;
    Wplo[idx] = *(const __hip_bfloat16*)&l;
}

// ---------------------------------------------------------------------------
// Kernel 1 (MFMA prep): HW = H@W, split-bf16 (hi+lo, 3 cross-term MFMAs).
// 256 blocks x 4 waves, wave w owns K-slice kt=w; partials combined through
// LDS; epilogue reads combined tile from LDS (no shuffles).
// UNCHANGED from round 3 (two structurally different preps benched neutral
// -> prep is off the critical path).
// ---------------------------------------------------------------------------
__global__ __launch_bounds__(256) void gat_prep(const float* __restrict__ H,
                                                const __hip_bfloat16* __restrict__ Wphi,
                                                const __hip_bfloat16* __restrict__ Wplo,
                                                float* __restrict__ expEl,
                                                __hip_bfloat16* __restrict__ Bp)
{
    __shared__ float Lp[4 * 16 * LSTR];   // 21.5 KB
    const int t    = threadIdx.x;
    const int wave = t >> 6;              // 0..3 = kt (K-slice of 32)
    const int lane = t & 63;
    const int j0   = blockIdx.x * 16;
    const int m16  = lane & 15, q = lane >> 4;
    const short* Whs = (const short*)Wphi;
    const short* Wls = (const short*)Wplo;
    const int kt = wave;

    // A-fragment: lane (q,m16) holds H[j0+m16][kt*32 + q*8 .. +7]
    const float* hp = H + (size_t)(j0 + m16) * FF + kt * 32 + q * 8;
    float4v x0 = *(const float4v*)hp;
    float4v x1 = *(const float4v*)(hp + 4);
    short8 ahi, alo;
    #pragma unroll
    for (int i = 0; i < 4; ++i) {
        const unsigned short h0 = bfb(x0[i]);
        ahi[i] = (short)h0;
        alo[i] = (short)bfb(x0[i] - bff(h0));
        const unsigned short h1 = bfb(x1[i]);
        ahi[4 + i] = (short)h1;
        alo[4 + i] = (short)bfb(x1[i] - bff(h1));
    }

    const short8* bh = (const short8*)(Whs + (size_t)(kt * 4 + q) * NC * 8);
    const short8* bl = (const short8*)(Wls + (size_t)(kt * 4 + q) * NC * 8);
    float4v acc[5] = {};
    #pragma unroll
    for (int nt = 0; nt < 5; ++nt) {
        short8 bhi = bh[nt * 16 + m16];
        short8 blo = bl[nt * 16 + m16];
        acc[nt] = __builtin_amdgcn_mfma_f32_16x16x32_bf16(ahi, bhi, acc[nt], 0, 0, 0);
        acc[nt] = __builtin_amdgcn_mfma_f32_16x16x32_bf16(alo, bhi, acc[nt], 0, 0, 0);
        acc[nt] = __builtin_amdgcn_mfma_f32_16x16x32_bf16(ahi, blo, acc[nt], 0, 0, 0);
    }

    // partial -> LDS (C/D layout: col=lane&15, row=(lane>>4)*4+reg)
    float* Lw = Lp + wave * (16 * LSTR);
    #pragma unroll
    for (int nt = 0; nt < 5; ++nt) {
        #pragma unroll
        for (int r = 0; r < 4; ++r)
            Lw[(q * 4 + r) * LSTR + nt * 16 + m16] = acc[nt][r];
    }
    __syncthreads();

    // ---- epilogue: 256 thr, thread (jl = t>>4, g = t&15) ----
    const int jl = t >> 4, g = t & 15;
    const float* Lr = Lp + jl * LSTR;
    const int jg = j0 + jl;
    const size_t base = ((size_t)((jg >> 5) * 4 + ((jg >> 3) & 3)) * NC) * 8 + (jg & 7);

    #pragma unroll
    for (int i = 0; i < 4; ++i) {
        const int c = g + 16 * i;                 // value col, h = c>>3
        const int h = (g >> 3) + 2 * i;
        const float er = expf(Lr[64 + h] + Lr[16 * LSTR + 64 + h] +
                              Lr[32 * LSTR + 64 + h] + Lr[48 * LSTR + 64 + h]);
        const float v = Lr[c] + Lr[16 * LSTR + c] +
                        Lr[32 * LSTR + c] + Lr[48 * LSTR + c];
        Bp[base + (size_t)c * 8] = __float2bfloat16(er * v);
    }
    float v64;
    if (g < 8) {
        v64 = expf(Lr[64 + g] + Lr[16 * LSTR + 64 + g] +
                   Lr[32 * LSTR + 64 + g] + Lr[48 * LSTR + 64 + g]);
    } else {
        v64 = (g == 8) ? 1.0f : 0.0f;
    }
    Bp[base + (size_t)(64 + g) * 8] = __float2bfloat16(v64);
    if (g >= 8) {
        const int h = g - 8;
        expEl[h * NN + jg] = expf(Lr[72 + h] + Lr[16 * LSTR + 72 + h] +
                                  Lr[32 * LSTR + 72 + h] + Lr[48 * LSTR + 72 + h]);
    }
}

// ---------------------------------------------------------------------------
// Kernel 2 (fused, block-local split-K): proven 512-thr/8-wave/grid-256
// structure. ONE isolated change vs round 3: B-fragment DOUBLE-BUFFER.
// Previously the 5 Bp loads for tile kt were issued and s_waitcnt'ed inside
// the same iteration: ~250-450 cyc of exposed L2 latency per kt with only
// 2 waves/SIMD to cover it (grid 256 = 1 block/CU, hard cap). Now kt+1's
// fragments are issued before kt's MFMAs consume buffer kt&1, so the wait
// lands ~400+ cyc after issue. A-prefetch ring deepened to 4 (8 KB/wave,
// 64 KB/CU in flight) for robustness. ~112 VGPR, no occupancy change.
// ---------------------------------------------------------------------------
__global__ __launch_bounds__(512) void gat_gemm(const float* __restrict__ A,
                                                const __hip_bfloat16* __restrict__ Bp,
                                                const float* __restrict__ expEl,
                                                float* __restrict__ out)
{
    __shared__ float Ls[8 * 16 * LSTR];   // 43 KB
    const int rb   = blockIdx.x;          // 0..255, 16 rows each
    const int wave = threadIdx.x >> 6;    // 0..7 = K-chunk
    const int lane = threadIdx.x & 63;
    const int m16  = lane & 15;
    const int q    = lane >> 4;
    const int row0 = rb * 16;

    float4v acc[5] = {};

    const int k0 = wave * 512;
    const unsigned int* Au = (const unsigned int*)A;
    const short8* bb = (const short8*)Bp;
    const unsigned int* arow = Au + (size_t)(row0 + m16) * NN + q * 8 + k0;

    // B index (short8 units): (ktg*4+q)*NC + nt*16 + m16, ktg = wave*16+kt
    const size_t bw = (size_t)(wave * 16) * 4 * NC + (size_t)q * NC + (size_t)m16;

    // A-prefetch ring, depth 4
    uint4v a0[4], a1[4];
    #pragma unroll
    for (int i = 0; i < 4; ++i) {
        a0[i] = *(const uint4v*)(arow + i * 32);
        a1[i] = *(const uint4v*)(arow + i * 32 + 4);
    }
    // B double-buffer: preload kt=0
    short8 bbuf[2][5];
    #pragma unroll
    for (int nt = 0; nt < 5; ++nt)
        bbuf[0][nt] = bb[bw + (size_t)nt * 16];

    #pragma unroll
    for (int kt = 0; kt < 16; ++kt) {
        const int cur = kt & 3;           // static after full unroll
        const int pb  = kt & 1, nb = pb ^ 1;

        // issue next B tile (consumed next iteration)
        if (kt + 1 < 16) {
            #pragma unroll
            for (int nt = 0; nt < 5; ++nt)
                bbuf[nb][nt] = bb[bw + (size_t)(kt + 1) * (4 * NC) + (size_t)nt * 16];
        }

        short8 afrag;
        afrag[0] = (short)(a0[cur][0] >> 16); afrag[1] = (short)(a0[cur][1] >> 16);
        afrag[2] = (short)(a0[cur][2] >> 16); afrag[3] = (short)(a0[cur][3] >> 16);
        afrag[4] = (short)(a1[cur][0] >> 16); afrag[5] = (short)(a1[cur][1] >> 16);
        afrag[6] = (short)(a1[cur][2] >> 16); afrag[7] = (short)(a1[cur][3] >> 16);

        if (kt + 4 < 16) {                // refill A ring
            a0[cur] = *(const uint4v*)(arow + (kt + 4) * 32);
            a1[cur] = *(const uint4v*)(arow + (kt + 4) * 32 + 4);
        }

        #pragma unroll
        for (int nt = 0; nt < 5; ++nt)
            acc[nt] = __builtin_amdgcn_mfma_f32_16x16x32_bf16(afrag, bbuf[pb][nt], acc[nt], 0, 0, 0);
    }

    // ---- partials -> LDS (stride LSTR=84: q-groups land 16 banks apart) ----
    float* Lw = Ls + wave * (16 * LSTR);
    #pragma unroll
    for (int nt = 0; nt < 5; ++nt) {
        #pragma unroll
        for (int r = 0; r < 4; ++r)       // C/D: col=lane&15, row=(lane>>4)*4+reg
            Lw[(q * 4 + r) * LSTR + nt * 16 + m16] = acc[nt][r];
    }
    __syncthreads();

    // ---- reduce 8 wave-partials + denom + elu + store (1024 outputs) ----
    #pragma unroll
    for (int p = threadIdx.x; p < 1024; p += 512) {
        const int il = p >> 6;            // local row
        const int c  = p & 63;            // h*8+u
        const int h  = c >> 3;
        float T = 0.f, S = 0.f, dg = 0.f;
        #pragma unroll
        for (int w = 0; w < 8; ++w) {
            const float* rowp = Ls + w * (16 * LSTR) + il * LSTR;
            T  += rowp[c];
            S  += rowp[64 + h];
            dg += rowp[72];
        }
        const float el = expEl[h * NN + row0 + il];
        const float denom = ((float)NN - dg) + el * S;
        const float x = el * T / denom;
        out[(size_t)(row0 + il) * 64 + c] = x > 0.f ? x : expf(x) - 1.f;
    }
}

extern "C" void kernel_launch(void* const* d_in, const int* in_sizes, int n_in,
                              void* d_out, int out_size, void* d_ws, size_t ws_size,
                              hipStream_t stream) {
    const float* A  = (const float*)d_in[0];
    const float* H  = (const float*)d_in[1];
    const float* W  = (const float*)d_in[2];
    const float* al = (const float*)d_in[3];
    const float* ar = (const float*)d_in[4];
    float* out = (float*)d_out;

    // workspace layout
    float* expEl = (float*)d_ws;                                    // 8*4096 f32 = 128 KB
    __hip_bfloat16* Bp   = (__hip_bfloat16*)((char*)d_ws + 131072); // 512*80*8 bf16 = 640 KB
    __hip_bfloat16* Wphi = (__hip_bfloat16*)((char*)d_ws + 131072 + 655360);          // 20 KB
    __hip_bfloat16* Wplo = (__hip_bfloat16*)((char*)d_ws + 131072 + 655360 + 20480);  // 20 KB

    gat_wsplit<<<40, 256, 0, stream>>>(W, al, ar, Wphi, Wplo);
    gat_prep<<<NN / 16, 256, 0, stream>>>(H, Wphi, Wplo, expEl, Bp);
    gat_gemm<<<NN / 16, 512, 0, stream>>>(A, Bp, expEl, out);
}